// Round 3
// baseline (138.988 us; speedup 1.0000x reference)
//
#include <hip/hip_runtime.h>
#include <hip/hip_bf16.h>

// Confusion-classification criterion (see reference):
//   pred = argmax(pred_logits[...,0:2])            (tie -> index 0)
//   cls  = g==1 ? (pred ? 1 : 2) : (pred ? 3 : 0)  (TP=1 FN=2 FP=3 TN=0)
//   loss = mean over B*N of -log_softmax(pred_confusion)[cls]
//
// R2 -> R3: maximize memory-level parallelism. Each thread processes two
// vec4-groups (v and v+half) with all 14 x 16B loads issued before any
// dependent compute (224 B/lane in flight). Two-kernel reduction, no memset.

#define NPART 2048

__device__ __forceinline__ float nll_one(float4 c, bool gpos, bool pred)
{
    int cls = gpos ? (pred ? 1 : 2) : (pred ? 3 : 0);
    float m   = fmaxf(fmaxf(c.x, c.y), fmaxf(c.z, c.w));
    float s   = __expf(c.x - m) + __expf(c.y - m) +
                __expf(c.z - m) + __expf(c.w - m);
    float lse = m + __logf(s);
    float xc  = (cls == 0) ? c.x : (cls == 1) ? c.y : (cls == 2) ? c.z : c.w;
    return lse - xc;
}

__global__ __launch_bounds__(256) void confusion_part_kernel(
    const float4* __restrict__ lg,    // logits: 1 float4 = 2 elements
    const float4* __restrict__ conf,  // confusion: 1 float4 = 1 element
    const int4*   __restrict__ tg,    // targets: 1 int4 = 4 elements
    const float2* __restrict__ lg2,   // scalar-tail views
    const int*    __restrict__ tg1,
    float* __restrict__ partials,     // [NPART]
    int total)
{
    const int idx    = blockIdx.x * blockDim.x + threadIdx.x;
    const int stride = gridDim.x * blockDim.x;
    const int nvec   = total >> 2;    // vec4 groups
    const int half   = nvec >> 1;     // pair groups v and v+half

    float acc = 0.0f;
    for (int v = idx; v < half; v += stride) {
        const int w = v + half;
        // ---- issue all independent loads first (14 x 16B) ----
        float4 lA0 = lg[2 * v];
        float4 lA1 = lg[2 * v + 1];
        float4 lB0 = lg[2 * w];
        float4 lB1 = lg[2 * w + 1];
        float4 a0  = conf[4 * v];
        float4 a1  = conf[4 * v + 1];
        float4 a2  = conf[4 * v + 2];
        float4 a3  = conf[4 * v + 3];
        float4 b0  = conf[4 * w];
        float4 b1  = conf[4 * w + 1];
        float4 b2  = conf[4 * w + 2];
        float4 b3  = conf[4 * w + 3];
        int4   ga  = tg[v];
        int4   gb  = tg[w];
        // ---- compute ----
        acc += nll_one(a0, ga.x == 1, lA0.y > lA0.x);
        acc += nll_one(a1, ga.y == 1, lA0.w > lA0.z);
        acc += nll_one(a2, ga.z == 1, lA1.y > lA1.x);
        acc += nll_one(a3, ga.w == 1, lA1.w > lA1.z);
        acc += nll_one(b0, gb.x == 1, lB0.y > lB0.x);
        acc += nll_one(b1, gb.y == 1, lB0.w > lB0.z);
        acc += nll_one(b2, gb.z == 1, lB1.y > lB1.x);
        acc += nll_one(b3, gb.w == 1, lB1.w > lB1.z);
    }

    // leftovers: odd vec4 group (if nvec odd) + scalar tail (total % 4)
    if (blockIdx.x == 0 && threadIdx.x == 0) {
        if (nvec & 1) {
            const int v = nvec - 1;
            float4 l0 = lg[2 * v];
            float4 l1 = lg[2 * v + 1];
            int4   g  = tg[v];
            acc += nll_one(conf[4 * v],     g.x == 1, l0.y > l0.x);
            acc += nll_one(conf[4 * v + 1], g.y == 1, l0.w > l0.z);
            acc += nll_one(conf[4 * v + 2], g.z == 1, l1.y > l1.x);
            acc += nll_one(conf[4 * v + 3], g.w == 1, l1.w > l1.z);
        }
        for (int i = nvec << 2; i < total; ++i) {
            float2 l = lg2[i];
            acc += nll_one(conf[i], tg1[i] == 1, l.y > l.x);
        }
    }

    // wave-64 reduce
    #pragma unroll
    for (int off = 32; off > 0; off >>= 1)
        acc += __shfl_down(acc, off, 64);

    __shared__ float wsum[4];
    int lane = threadIdx.x & 63;
    int wid  = threadIdx.x >> 6;
    if (lane == 0) wsum[wid] = acc;
    __syncthreads();

    if (threadIdx.x == 0)
        partials[blockIdx.x] = wsum[0] + wsum[1] + wsum[2] + wsum[3];
}

__global__ __launch_bounds__(256) void confusion_final_kernel(
    const float* __restrict__ partials, float* __restrict__ out,
    int npart, float inv_total)
{
    float acc = 0.0f;
    for (int i = threadIdx.x; i < npart; i += 256)
        acc += partials[i];

    #pragma unroll
    for (int off = 32; off > 0; off >>= 1)
        acc += __shfl_down(acc, off, 64);

    __shared__ float wsum[4];
    int lane = threadIdx.x & 63;
    int wid  = threadIdx.x >> 6;
    if (lane == 0) wsum[wid] = acc;
    __syncthreads();

    if (threadIdx.x == 0)
        out[0] = (wsum[0] + wsum[1] + wsum[2] + wsum[3]) * inv_total;
}

extern "C" void kernel_launch(void* const* d_in, const int* in_sizes, int n_in,
                              void* d_out, int out_size, void* d_ws, size_t ws_size,
                              hipStream_t stream)
{
    const float4* lg    = (const float4*)d_in[0];
    const float4* conf  = (const float4*)d_in[1];
    const int4*   tg    = (const int4*)d_in[2];
    const float2* lg2   = (const float2*)d_in[0];
    const int*    tg1   = (const int*)d_in[2];
    float*        out   = (float*)d_out;
    float*        parts = (float*)d_ws;       // NPART floats (8 KB)

    const int total = in_sizes[2];            // B*N = 4,194,304

    confusion_part_kernel<<<NPART, 256, 0, stream>>>(
        lg, conf, tg, lg2, tg1, parts, total);
    confusion_final_kernel<<<1, 256, 0, stream>>>(
        parts, out, NPART, 1.0f / (float)total);
}

// Round 4
// 135.645 us; speedup vs baseline: 1.0246x; 1.0246x over previous
//
#include <hip/hip_runtime.h>
#include <hip/hip_bf16.h>

// Confusion-classification criterion (see reference):
//   pred = argmax(pred_logits[...,0:2])            (tie -> index 0)
//   cls  = g==1 ? (pred ? 1 : 2) : (pred ? 3 : 0)  (TP=1 FN=2 FP=3 TN=0)
//   loss = mean over B*N of -log_softmax(pred_confusion)[cls]
//
// R3 -> R4: perfect per-instruction coalescing. Element index
// e = base + k*blockDim + tid, so every load instruction is unit-stride:
// conf float4 (16B/lane), logits float2 (8B/lane), targets int (4B/lane).
// K=8 elements/thread, all 24 loads issued before any compute.

#define NPART 2048
#define K_ELEMS 8

__device__ __forceinline__ float nll_one(float4 c, bool gpos, bool pred)
{
    int cls = gpos ? (pred ? 1 : 2) : (pred ? 3 : 0);
    float m   = fmaxf(fmaxf(c.x, c.y), fmaxf(c.z, c.w));
    float s   = __expf(c.x - m) + __expf(c.y - m) +
                __expf(c.z - m) + __expf(c.w - m);
    float lse = m + __logf(s);
    float xc  = (cls == 0) ? c.x : (cls == 1) ? c.y : (cls == 2) ? c.z : c.w;
    return lse - xc;
}

__global__ __launch_bounds__(256) void confusion_part_kernel(
    const float2* __restrict__ lg,    // [total] logit pairs
    const float4* __restrict__ conf,  // [total] confusion rows
    const int*    __restrict__ tg,    // [total] targets
    float* __restrict__ partials,     // [NPART]
    int total)
{
    const int tid   = threadIdx.x;
    const int bdim  = blockDim.x;
    const int chunk = bdim * K_ELEMS;              // elements per block-pass

    float acc = 0.0f;
    for (int base = blockIdx.x * chunk; base < total;
         base += gridDim.x * chunk) {

        if (base + chunk <= total) {
            // ---- full tile: issue all 24 coalesced loads first ----
            float4 c[K_ELEMS];
            float2 l[K_ELEMS];
            int    g[K_ELEMS];
            #pragma unroll
            for (int k = 0; k < K_ELEMS; ++k) {
                int e = base + k * bdim + tid;
                c[k] = conf[e];
                l[k] = lg[e];
                g[k] = tg[e];
            }
            #pragma unroll
            for (int k = 0; k < K_ELEMS; ++k)
                acc += nll_one(c[k], g[k] == 1, l[k].y > l[k].x);
        } else {
            // ---- ragged tail tile ----
            for (int k = 0; k < K_ELEMS; ++k) {
                int e = base + k * bdim + tid;
                if (e < total) {
                    float2 l = lg[e];
                    acc += nll_one(conf[e], tg[e] == 1, l.y > l.x);
                }
            }
        }
    }

    // wave-64 reduce
    #pragma unroll
    for (int off = 32; off > 0; off >>= 1)
        acc += __shfl_down(acc, off, 64);

    __shared__ float wsum[4];
    int lane = tid & 63;
    int wid  = tid >> 6;
    if (lane == 0) wsum[wid] = acc;
    __syncthreads();

    if (tid == 0)
        partials[blockIdx.x] = wsum[0] + wsum[1] + wsum[2] + wsum[3];
}

__global__ __launch_bounds__(256) void confusion_final_kernel(
    const float* __restrict__ partials, float* __restrict__ out,
    int npart, float inv_total)
{
    float acc = 0.0f;
    for (int i = threadIdx.x; i < npart; i += 256)
        acc += partials[i];

    #pragma unroll
    for (int off = 32; off > 0; off >>= 1)
        acc += __shfl_down(acc, off, 64);

    __shared__ float wsum[4];
    int lane = threadIdx.x & 63;
    int wid  = threadIdx.x >> 6;
    if (lane == 0) wsum[wid] = acc;
    __syncthreads();

    if (threadIdx.x == 0)
        out[0] = (wsum[0] + wsum[1] + wsum[2] + wsum[3]) * inv_total;
}

extern "C" void kernel_launch(void* const* d_in, const int* in_sizes, int n_in,
                              void* d_out, int out_size, void* d_ws, size_t ws_size,
                              hipStream_t stream)
{
    const float2* lg    = (const float2*)d_in[0];
    const float4* conf  = (const float4*)d_in[1];
    const int*    tg    = (const int*)d_in[2];
    float*        out   = (float*)d_out;
    float*        parts = (float*)d_ws;       // NPART floats (8 KB)

    const int total = in_sizes[2];            // B*N = 4,194,304

    confusion_part_kernel<<<NPART, 256, 0, stream>>>(
        lg, conf, tg, parts, total);
    confusion_final_kernel<<<1, 256, 0, stream>>>(
        parts, out, NPART, 1.0f / (float)total);
}

// Round 5
// 135.209 us; speedup vs baseline: 1.0280x; 1.0032x over previous
//
#include <hip/hip_runtime.h>
#include <hip/hip_bf16.h>

// Confusion-classification criterion (see reference):
//   pred = argmax(pred_logits[...,0:2])            (tie -> index 0)
//   cls  = g==1 ? (pred ? 1 : 2) : (pred ? 3 : 0)  (TP=1 FN=2 FP=3 TN=0)
//   loss = mean over B*N of -log_softmax(pred_confusion)[cls]
//
// R4 -> R5: finer tiling for dispatch overlap. 4096 blocks x 256 thr x K=4
// (exactly one pass over 4.19M elements). Per-instruction unit-stride loads
// (e = base + k*bdim + tid). Final kernel reads partials as float4.

#define NPART 4096
#define K_ELEMS 4

__device__ __forceinline__ float nll_one(float4 c, bool gpos, bool pred)
{
    int cls = gpos ? (pred ? 1 : 2) : (pred ? 3 : 0);
    float m   = fmaxf(fmaxf(c.x, c.y), fmaxf(c.z, c.w));
    float s   = __expf(c.x - m) + __expf(c.y - m) +
                __expf(c.z - m) + __expf(c.w - m);
    float lse = m + __logf(s);
    float xc  = (cls == 0) ? c.x : (cls == 1) ? c.y : (cls == 2) ? c.z : c.w;
    return lse - xc;
}

__global__ __launch_bounds__(256) void confusion_part_kernel(
    const float2* __restrict__ lg,    // [total] logit pairs
    const float4* __restrict__ conf,  // [total] confusion rows
    const int*    __restrict__ tg,    // [total] targets
    float* __restrict__ partials,     // [NPART]
    int total)
{
    const int tid   = threadIdx.x;
    const int bdim  = blockDim.x;
    const int chunk = bdim * K_ELEMS;              // elements per block-pass

    float acc = 0.0f;
    for (int base = blockIdx.x * chunk; base < total;
         base += gridDim.x * chunk) {

        if (base + chunk <= total) {
            // full tile: issue all coalesced loads first
            float4 c[K_ELEMS];
            float2 l[K_ELEMS];
            int    g[K_ELEMS];
            #pragma unroll
            for (int k = 0; k < K_ELEMS; ++k) {
                int e = base + k * bdim + tid;
                c[k] = conf[e];
                l[k] = lg[e];
                g[k] = tg[e];
            }
            #pragma unroll
            for (int k = 0; k < K_ELEMS; ++k)
                acc += nll_one(c[k], g[k] == 1, l[k].y > l[k].x);
        } else {
            // ragged tail tile (not hit at B*N = 4,194,304)
            for (int k = 0; k < K_ELEMS; ++k) {
                int e = base + k * bdim + tid;
                if (e < total) {
                    float2 l = lg[e];
                    acc += nll_one(conf[e], tg[e] == 1, l.y > l.x);
                }
            }
        }
    }

    // wave-64 reduce
    #pragma unroll
    for (int off = 32; off > 0; off >>= 1)
        acc += __shfl_down(acc, off, 64);

    __shared__ float wsum[4];
    int lane = tid & 63;
    int wid  = tid >> 6;
    if (lane == 0) wsum[wid] = acc;
    __syncthreads();

    if (tid == 0)
        partials[blockIdx.x] = wsum[0] + wsum[1] + wsum[2] + wsum[3];
}

__global__ __launch_bounds__(256) void confusion_final_kernel(
    const float4* __restrict__ partials, float* __restrict__ out,
    int nquads, float inv_total)
{
    float acc = 0.0f;
    for (int i = threadIdx.x; i < nquads; i += 256) {
        float4 p = partials[i];
        acc += (p.x + p.y) + (p.z + p.w);
    }

    #pragma unroll
    for (int off = 32; off > 0; off >>= 1)
        acc += __shfl_down(acc, off, 64);

    __shared__ float wsum[4];
    int lane = threadIdx.x & 63;
    int wid  = threadIdx.x >> 6;
    if (lane == 0) wsum[wid] = acc;
    __syncthreads();

    if (threadIdx.x == 0)
        out[0] = (wsum[0] + wsum[1] + wsum[2] + wsum[3]) * inv_total;
}

extern "C" void kernel_launch(void* const* d_in, const int* in_sizes, int n_in,
                              void* d_out, int out_size, void* d_ws, size_t ws_size,
                              hipStream_t stream)
{
    const float2* lg    = (const float2*)d_in[0];
    const float4* conf  = (const float4*)d_in[1];
    const int*    tg    = (const int*)d_in[2];
    float*        out   = (float*)d_out;
    float*        parts = (float*)d_ws;       // NPART floats (16 KB)

    const int total = in_sizes[2];            // B*N = 4,194,304

    confusion_part_kernel<<<NPART, 256, 0, stream>>>(
        lg, conf, tg, parts, total);
    confusion_final_kernel<<<1, 256, 0, stream>>>(
        (const float4*)parts, out, NPART / 4, 1.0f / (float)total);
}